// Round 8
// baseline (388.520 us; speedup 1.0000x reference)
//
#include <hip/hip_runtime.h>

#define Bb_ 4
#define Hh_ 16
#define Ss_ 1024
#define DH 64
#define MAXLEN 2048
#define BH (Bb_*Hh_)
#define LDST 72   // 64 + 8 pad (bf16 elems) -> 144B row stride, 16B aligned

typedef __attribute__((ext_vector_type(8))) short short8;
typedef __attribute__((ext_vector_type(4))) float floatx4;
typedef __attribute__((ext_vector_type(4))) unsigned short ushort4v;

static __device__ __forceinline__ unsigned short f2bf(float f) {
    unsigned int u = __builtin_bit_cast(unsigned int, f);
    u = (u + 0x7fffu + ((u >> 16) & 1u)) >> 16;   // RNE
    return (unsigned short)u;
}

// Stage a 128x64 fp32 tile (row stride 64) -> bf16 LDS tile (row stride LDST)
static __device__ __forceinline__ void stage_tile(unsigned short* lds,
                                                  const float* __restrict__ g,
                                                  int tid) {
#pragma unroll
    for (int it = 0; it < 8; ++it) {
        int idx = it * 1024 + tid * 4;
        int row = idx >> 6, col = idx & 63;
        const float4 v = *reinterpret_cast<const float4*>(g + row * 64 + col);
        ushort4v o = { f2bf(v.x), f2bf(v.y), f2bf(v.z), f2bf(v.w) };
        *reinterpret_cast<ushort4v*>(lds + row * LDST + col) = o;
    }
}

// ---- Kernel A: ctx = clip(sum_t sigmoid(qk/8)*t), then pemb[bh,t,:] bf16 ----
__global__ __launch_bounds__(256, 2)
void ctx_emb_kernel(const float* __restrict__ q, const float* __restrict__ k,
                    const float* __restrict__ tb,
                    unsigned short* __restrict__ pemb) {
    __shared__ __align__(16) unsigned short Ab[128 * LDST];
    __shared__ __align__(16) unsigned short Kb[128 * LDST];
    __shared__ float sh_ctx[128];

    int bx = blockIdx.x;
    int bh = bx >> 3, mt = bx & 7;
    int m0 = mt << 7;
    int tid = threadIdx.x;
    int lane = tid & 63, w = tid >> 6;
    int lo = lane & 15, quad = lane >> 4;

    stage_tile(Ab, q + (size_t)(bh * Ss_ + m0) * DH, tid);
    __syncthreads();

    short8 afr[2][2];
#pragma unroll
    for (int i = 0; i < 2; ++i)
#pragma unroll
        for (int k2 = 0; k2 < 2; ++k2)
            afr[i][k2] = *reinterpret_cast<const short8*>(
                &Ab[(w * 32 + i * 16 + lo) * LDST + k2 * 32 + quad * 8]);

    float rp[2][4];
#pragma unroll
    for (int i = 0; i < 2; ++i)
#pragma unroll
        for (int r = 0; r < 4; ++r) rp[i][r] = 0.f;

    for (int tt = 0; tt < 8; ++tt) {
        int t0 = tt << 7;
        __syncthreads();  // previous iter's Kb frag reads done
        stage_tile(Kb, k + (size_t)(bh * Ss_ + t0) * DH, tid);
        __syncthreads();

#pragma unroll
        for (int j = 0; j < 8; ++j) {
            short8 b0 = *reinterpret_cast<const short8*>(
                &Kb[(j * 16 + lo) * LDST + 0 + quad * 8]);
            short8 b1 = *reinterpret_cast<const short8*>(
                &Kb[(j * 16 + lo) * LDST + 32 + quad * 8]);
            float tcol = (float)(t0 + j * 16 + lo);
#pragma unroll
            for (int i = 0; i < 2; ++i) {
                floatx4 c = {0.f, 0.f, 0.f, 0.f};
                c = __builtin_amdgcn_mfma_f32_16x16x32_bf16(afr[i][0], b0, c, 0, 0, 0);
                c = __builtin_amdgcn_mfma_f32_16x16x32_bf16(afr[i][1], b1, c, 0, 0, 0);
#pragma unroll
                for (int r = 0; r < 4; ++r) {
                    float x = c[r] * 0.125f;
                    float e = __expf(-x);
                    float g = __builtin_amdgcn_rcpf(1.0f + e);
                    rp[i][r] += g * tcol;
                }
            }
        }
    }

#pragma unroll
    for (int i = 0; i < 2; ++i)
#pragma unroll
        for (int r = 0; r < 4; ++r) {
            float v = rp[i][r];
            v += __shfl_xor(v, 1);
            v += __shfl_xor(v, 2);
            v += __shfl_xor(v, 4);
            v += __shfl_xor(v, 8);
            rp[i][r] = v;
        }

    if (lo == 0) {
#pragma unroll
        for (int i = 0; i < 2; ++i)
#pragma unroll
            for (int r = 0; r < 4; ++r) {
                int row = w * 32 + i * 16 + quad * 4 + r;
                sh_ctx[row] = fminf(fmaxf(rp[i][r], 0.f), (float)(MAXLEN - 2));
            }
    }
    __syncthreads();

    // Interpolate pos_table at sh_ctx -> bf16 pemb[bh, m0+row, 0:64]
    {
        int rsub = tid >> 4;       // 0..15
        int d0 = (tid & 15) * 4;   // 0..60
#pragma unroll
        for (int pass = 0; pass < 8; ++pass) {
            int row = pass * 16 + rsub;
            float c = sh_ctx[row];
            int fl = (int)c;
            float fr = c - (float)fl;
            int ce = min(fl + 1, MAXLEN - 1);
            const float4 e0 = *reinterpret_cast<const float4*>(tb + fl * DH + d0);
            const float4 e1 = *reinterpret_cast<const float4*>(tb + ce * DH + d0);
            ushort4v o = { f2bf(e0.x + fr * (e1.x - e0.x)),
                           f2bf(e0.y + fr * (e1.y - e0.y)),
                           f2bf(e0.z + fr * (e1.z - e0.z)),
                           f2bf(e0.w + fr * (e1.w - e0.w)) };
            *reinterpret_cast<ushort4v*>(
                pemb + (size_t)(bh * Ss_ + m0 + row) * DH + d0) = o;
        }
    }
}

// ---- Kernel B: m-strip, flat 64-group loop, reg-prefetched B, cached stores -
// Per block: 128 q-rows x all 1024 cols. No barriers after A-stage; stores
// spread uniformly through the loop -> continuous per-CU store stream.
__global__ __launch_bounds__(256, 2)
void bias_kernel(const float* __restrict__ q,
                 const unsigned short* __restrict__ pemb,
                 float* __restrict__ out) {
    __shared__ __align__(16) unsigned short Ab[128 * LDST];

    int bx = blockIdx.x;
    int bh = bx >> 3, mt = bx & 7;
    int m0 = mt << 7;
    int tid = threadIdx.x;
    int lane = tid & 63, w = tid >> 6;
    int lo = lane & 15, quad = lane >> 4;

    stage_tile(Ab, q + (size_t)(bh * Ss_ + m0) * DH, tid);
    __syncthreads();

    short8 afr[2][2];
#pragma unroll
    for (int i = 0; i < 2; ++i)
#pragma unroll
        for (int k2 = 0; k2 < 2; ++k2)
            afr[i][k2] = *reinterpret_cast<const short8*>(
                &Ab[(w * 32 + i * 16 + lo) * LDST + k2 * 32 + quad * 8]);

    // B stream: col(g) = g*16 + lo, g = 0..63 covers all 1024 columns.
    const unsigned short* bp = pemb + ((size_t)bh * Ss_ + lo) * DH + quad * 8;
    // Output row bases for this lane (i=0 and i=1 sub-tiles).
    float* o0 = out + (size_t)(bh * Ss_ + m0 + w * 32 + quad * 4) * Ss_;
    float* o1 = o0 + (size_t)16 * Ss_;

    short8 cb0 = *reinterpret_cast<const short8*>(bp);
    short8 cb1 = *reinterpret_cast<const short8*>(bp + 32);

#pragma unroll 1
    for (int g = 0; g < 64; ++g) {
        short8 nb0 = cb0, nb1 = cb1;
        if (g < 63) {
            const unsigned short* np = bp + (size_t)(g + 1) * 1024;  // 16 rows * 64
            nb0 = *reinterpret_cast<const short8*>(np);
            nb1 = *reinterpret_cast<const short8*>(np + 32);
        }

        floatx4 a0 = {0.f, 0.f, 0.f, 0.f};
        floatx4 a1 = {0.f, 0.f, 0.f, 0.f};
        a0 = __builtin_amdgcn_mfma_f32_16x16x32_bf16(afr[0][0], cb0, a0, 0, 0, 0);
        a0 = __builtin_amdgcn_mfma_f32_16x16x32_bf16(afr[0][1], cb1, a0, 0, 0, 0);
        a1 = __builtin_amdgcn_mfma_f32_16x16x32_bf16(afr[1][0], cb0, a1, 0, 0, 0);
        a1 = __builtin_amdgcn_mfma_f32_16x16x32_bf16(afr[1][1], cb1, a1, 0, 0, 0);

        int colg = g * 16 + lo;
#pragma unroll
        for (int r = 0; r < 4; ++r) {
            o0[(size_t)r * Ss_ + colg] = a0[r];
            o1[(size_t)r * Ss_ + colg] = a1[r];
        }

        cb0 = nb0;
        cb1 = nb1;
    }
}

extern "C" void kernel_launch(void* const* d_in, const int* in_sizes, int n_in,
                              void* d_out, int out_size, void* d_ws, size_t ws_size,
                              hipStream_t stream) {
    const float* q  = (const float*)d_in[0];
    const float* k  = (const float*)d_in[1];
    const float* tb = (const float*)d_in[2];
    unsigned short* pemb = (unsigned short*)d_ws;   // BH*S*64 bf16 = 8 MB
    float* out = (float*)d_out;

    ctx_emb_kernel<<<BH * 8, 256, 0, stream>>>(q, k, tb, pemb);
    bias_kernel<<<BH * 8, 256, 0, stream>>>(q, pemb, out);
}

// Round 9
// 327.436 us; speedup vs baseline: 1.1866x; 1.1866x over previous
//
#include <hip/hip_runtime.h>

#define Bb_ 4
#define Hh_ 16
#define Ss_ 1024
#define DH 64
#define MAXLEN 2048
#define BH (Bb_*Hh_)
#define LDST 72   // 64 + 8 pad (bf16 elems) -> 144B row stride, 16B aligned
#define SW 132    // fp32 epilogue scratch stride (128 + 4 pad words)

typedef __attribute__((ext_vector_type(8))) short short8;
typedef __attribute__((ext_vector_type(4))) float floatx4;
typedef __attribute__((ext_vector_type(4))) unsigned short ushort4v;

static __device__ __forceinline__ unsigned short f2bf(float f) {
    unsigned int u = __builtin_bit_cast(unsigned int, f);
    u = (u + 0x7fffu + ((u >> 16) & 1u)) >> 16;   // RNE
    return (unsigned short)u;
}

// Stage a 128x64 fp32 tile (row stride 64) -> bf16 LDS tile (row stride LDST)
static __device__ __forceinline__ void stage_tile(unsigned short* lds,
                                                  const float* __restrict__ g,
                                                  int tid) {
#pragma unroll
    for (int it = 0; it < 8; ++it) {
        int idx = it * 1024 + tid * 4;
        int row = idx >> 6, col = idx & 63;
        const float4 v = *reinterpret_cast<const float4*>(g + row * 64 + col);
        ushort4v o = { f2bf(v.x), f2bf(v.y), f2bf(v.z), f2bf(v.w) };
        *reinterpret_cast<ushort4v*>(lds + row * LDST + col) = o;
    }
}

// -- Kernel A: ctx = clip(sum_t sigmoid(qk/8)*t, 0, 2046) + per-tile min/max --
__global__ __launch_bounds__(256, 2)
void ctx_kernel(const float* __restrict__ q, const float* __restrict__ k,
                float* __restrict__ ctx, float2* __restrict__ mm) {
    __shared__ __align__(16) unsigned short Ab[128 * LDST];
    __shared__ __align__(16) unsigned short Kb[128 * LDST];
    __shared__ float sh_ctx[128];

    int bx = blockIdx.x;
    int bh = bx >> 3, mt = bx & 7;
    int m0 = mt << 7;
    int tid = threadIdx.x;
    int lane = tid & 63, w = tid >> 6;
    int lo = lane & 15, quad = lane >> 4;

    stage_tile(Ab, q + (size_t)(bh * Ss_ + m0) * DH, tid);
    __syncthreads();

    short8 afr[2][2];
#pragma unroll
    for (int i = 0; i < 2; ++i)
#pragma unroll
        for (int k2 = 0; k2 < 2; ++k2)
            afr[i][k2] = *reinterpret_cast<const short8*>(
                &Ab[(w * 32 + i * 16 + lo) * LDST + k2 * 32 + quad * 8]);

    float rp[2][4];
#pragma unroll
    for (int i = 0; i < 2; ++i)
#pragma unroll
        for (int r = 0; r < 4; ++r) rp[i][r] = 0.f;

    for (int tt = 0; tt < 8; ++tt) {
        int t0 = tt << 7;
        __syncthreads();  // previous iter's Kb frag reads done
        stage_tile(Kb, k + (size_t)(bh * Ss_ + t0) * DH, tid);
        __syncthreads();

#pragma unroll
        for (int j = 0; j < 8; ++j) {
            short8 b0 = *reinterpret_cast<const short8*>(
                &Kb[(j * 16 + lo) * LDST + 0 + quad * 8]);
            short8 b1 = *reinterpret_cast<const short8*>(
                &Kb[(j * 16 + lo) * LDST + 32 + quad * 8]);
            float tcol = (float)(t0 + j * 16 + lo);
#pragma unroll
            for (int i = 0; i < 2; ++i) {
                floatx4 c = {0.f, 0.f, 0.f, 0.f};
                c = __builtin_amdgcn_mfma_f32_16x16x32_bf16(afr[i][0], b0, c, 0, 0, 0);
                c = __builtin_amdgcn_mfma_f32_16x16x32_bf16(afr[i][1], b1, c, 0, 0, 0);
#pragma unroll
                for (int r = 0; r < 4; ++r) {
                    float x = c[r] * 0.125f;
                    float e = __expf(-x);
                    float g = __builtin_amdgcn_rcpf(1.0f + e);
                    rp[i][r] += g * tcol;
                }
            }
        }
    }

    // reduce across the 16 lanes (cols) sharing each row
#pragma unroll
    for (int i = 0; i < 2; ++i)
#pragma unroll
        for (int r = 0; r < 4; ++r) {
            float v = rp[i][r];
            v += __shfl_xor(v, 1);
            v += __shfl_xor(v, 2);
            v += __shfl_xor(v, 4);
            v += __shfl_xor(v, 8);
            rp[i][r] = v;
        }

    if (lo == 0) {
#pragma unroll
        for (int i = 0; i < 2; ++i)
#pragma unroll
            for (int r = 0; r < 4; ++r) {
                int lr = w * 32 + i * 16 + quad * 4 + r;
                float v = fminf(fmaxf(rp[i][r], 0.f), (float)(MAXLEN - 2));
                sh_ctx[lr] = v;
                ctx[bh * Ss_ + m0 + lr] = v;
            }
    }
    __syncthreads();

    // Block min/max of the 128 ctx values -> mm[bh*8+mt]
    if (tid < 64) {
        float a = sh_ctx[tid], b = sh_ctx[tid + 64];
        float mn = fminf(a, b), mx = fmaxf(a, b);
#pragma unroll
        for (int off = 1; off < 64; off <<= 1) {
            mn = fminf(mn, __shfl_xor(mn, off));
            mx = fmaxf(mx, __shfl_xor(mx, off));
        }
        if (tid == 0) mm[bh * 8 + mt] = make_float2(mn, mx);
    }
}

// -- Kernel B: bias = Q . pos_emb^T. Fast path when ctx is uniform over bh
//    (pos_emb rows all identical -> each output row is one constant):
//    fp32 dots + streaming row-constant NT writes. Else: proven R7 GEMM path.
__global__ __launch_bounds__(256, 4)
void bias_kernel(const float* __restrict__ q, const float* __restrict__ tb,
                 const float* __restrict__ ctx, const float2* __restrict__ mm,
                 float* __restrict__ out) {
    __shared__ __align__(16) unsigned char smem[2 * 128 * LDST * 2];

    int bx = blockIdx.x;
    int bh = bx >> 6;
    int mt = (bx >> 3) & 7;
    int nt = bx & 7;
    int m0 = mt << 7, n0 = nt << 7;
    int tid = threadIdx.x;
    int lane = tid & 63, w = tid >> 6;
    int lo = lane & 15, quad = lane >> 4;

    // Uniformity check over all 8 m-tiles of this bh (block-uniform result)
    float mn = 3.0e38f, mx = -3.0e38f;
#pragma unroll
    for (int j = 0; j < 8; ++j) {
        float2 p = mm[bh * 8 + j];
        mn = fminf(mn, p.x);
        mx = fmaxf(mx, p.y);
    }

    if (mn == mx) {
        // ---------- FAST PATH: pos_emb identical for every t ----------
        float* pr = reinterpret_cast<float*>(smem);        // [64] fp32 emb row
        float* sc = pr + 64;                               // [128] row constants

        float v = mn;
        int fl = (int)v;
        float fr = v - (float)fl;
        int ce = min(fl + 1, MAXLEN - 1);
        if (tid < 16) {
            int d0 = tid * 4;
            const float4 e0 = *reinterpret_cast<const float4*>(tb + fl * DH + d0);
            const float4 e1 = *reinterpret_cast<const float4*>(tb + ce * DH + d0);
            pr[d0 + 0] = e0.x + fr * (e1.x - e0.x);
            pr[d0 + 1] = e0.y + fr * (e1.y - e0.y);
            pr[d0 + 2] = e0.z + fr * (e1.z - e0.z);
            pr[d0 + 3] = e0.w + fr * (e1.w - e0.w);
        }
        __syncthreads();

        // fp32 dots: 2 threads per row (halves), combine via shfl_xor(1)
        {
            int row = tid >> 1, half = tid & 1;
            const float* qr = q + (size_t)(bh * Ss_ + m0 + row) * DH + half * 32;
            const float* ph = pr + half * 32;
            float s = 0.f;
#pragma unroll
            for (int d = 0; d < 32; d += 4) {
                const float4 qq = *reinterpret_cast<const float4*>(qr + d);
                s += qq.x * ph[d] + qq.y * ph[d + 1] + qq.z * ph[d + 2] +
                     qq.w * ph[d + 3];
            }
            s += __shfl_xor(s, 1);
            if (half == 0) sc[row] = s;
        }
        __syncthreads();

        // Stream the 128x128 tile: each wave-inst writes 1 KB of full lines
#pragma unroll
        for (int it = 0; it < 16; ++it) {
            int flat = (it * 256 + tid) * 4;
            int lrow = flat >> 7, col = flat & 127;
            float c = sc[lrow];
            floatx4 vv = {c, c, c, c};
            __builtin_nontemporal_store(
                vv, reinterpret_cast<floatx4*>(
                        out + (size_t)(bh * Ss_ + m0 + lrow) * Ss_ + n0 + col));
        }
        return;
    }

    // ---------- SLOW PATH: R7-proven tile GEMM ----------
    unsigned short* Ab = reinterpret_cast<unsigned short*>(smem);
    unsigned short* Pb = Ab + 128 * LDST;
    float* scratch = reinterpret_cast<float*>(smem);

    stage_tile(Ab, q + (size_t)(bh * Ss_ + m0) * DH, tid);

    {
        int rsub = tid >> 4;       // 0..15
        int d0 = (tid & 15) * 4;   // 0..60
#pragma unroll
        for (int pass = 0; pass < 8; ++pass) {
            int row = pass * 16 + rsub;
            float c = ctx[bh * Ss_ + n0 + row];
            int fl = (int)c;
            float fr = c - (float)fl;
            int ce = min(fl + 1, MAXLEN - 1);
            const float4 e0 = *reinterpret_cast<const float4*>(tb + fl * DH + d0);
            const float4 e1 = *reinterpret_cast<const float4*>(tb + ce * DH + d0);
            ushort4v o = { f2bf(e0.x + fr * (e1.x - e0.x)),
                           f2bf(e0.y + fr * (e1.y - e0.y)),
                           f2bf(e0.z + fr * (e1.z - e0.z)),
                           f2bf(e0.w + fr * (e1.w - e0.w)) };
            *reinterpret_cast<ushort4v*>(&Pb[row * LDST + d0]) = o;
        }
    }
    __syncthreads();

    short8 afr[2][2];
#pragma unroll
    for (int i = 0; i < 2; ++i)
#pragma unroll
        for (int k2 = 0; k2 < 2; ++k2)
            afr[i][k2] = *reinterpret_cast<const short8*>(
                &Ab[(w * 32 + i * 16 + lo) * LDST + k2 * 32 + quad * 8]);

    floatx4 acc[2][8];
#pragma unroll
    for (int i = 0; i < 2; ++i)
#pragma unroll
        for (int j = 0; j < 8; ++j) acc[i][j] = (floatx4){0.f, 0.f, 0.f, 0.f};

#pragma unroll
    for (int j = 0; j < 8; ++j) {
        short8 b0 = *reinterpret_cast<const short8*>(
            &Pb[(j * 16 + lo) * LDST + 0 + quad * 8]);
        short8 b1 = *reinterpret_cast<const short8*>(
            &Pb[(j * 16 + lo) * LDST + 32 + quad * 8]);
#pragma unroll
        for (int i = 0; i < 2; ++i) {
            acc[i][j] = __builtin_amdgcn_mfma_f32_16x16x32_bf16(afr[i][0], b0, acc[i][j], 0, 0, 0);
            acc[i][j] = __builtin_amdgcn_mfma_f32_16x16x32_bf16(afr[i][1], b1, acc[i][j], 0, 0, 0);
        }
    }

    // Epilogue: LDS transpose -> contiguous dwordx4 nontemporal stores.
#pragma unroll
    for (int i = 0; i < 2; ++i) {
        __syncthreads();
#pragma unroll
        for (int j = 0; j < 8; ++j)
#pragma unroll
            for (int r = 0; r < 4; ++r) {
                int lrow = w * 16 + quad * 4 + r;
                scratch[lrow * SW + j * 16 + lo] = acc[i][j][r];
            }
        __syncthreads();
#pragma unroll
        for (int it = 0; it < 8; ++it) {
            int flat = it * 1024 + tid * 4;
            int lrow = flat >> 7, col = flat & 127;
            floatx4 vv = *reinterpret_cast<const floatx4*>(&scratch[lrow * SW + col]);
            int grow = m0 + (lrow >> 4) * 32 + i * 16 + (lrow & 15);
            __builtin_nontemporal_store(
                vv, reinterpret_cast<floatx4*>(
                        out + (size_t)(bh * Ss_ + grow) * Ss_ + n0 + col));
        }
    }
}

extern "C" void kernel_launch(void* const* d_in, const int* in_sizes, int n_in,
                              void* d_out, int out_size, void* d_ws, size_t ws_size,
                              hipStream_t stream) {
    const float* q  = (const float*)d_in[0];
    const float* k  = (const float*)d_in[1];
    const float* tb = (const float*)d_in[2];
    float* ctx = (float*)d_ws;                       // BH*S floats = 256 KB
    float2* mm = (float2*)((float*)d_ws + BH * Ss_); // BH*8 float2
    float* out = (float*)d_out;

    ctx_kernel<<<BH * 8, 256, 0, stream>>>(q, k, ctx, mm);
    bias_kernel<<<BH * 64, 256, 0, stream>>>(q, tb, ctx, mm, out);
}

// Round 10
// 322.142 us; speedup vs baseline: 1.2061x; 1.0164x over previous
//
#include <hip/hip_runtime.h>

#define Bb_ 4
#define Hh_ 16
#define Ss_ 1024
#define DH 64
#define MAXLEN 2048
#define BH (Bb_*Hh_)
#define LDST 72   // 64 + 8 pad (bf16 elems) -> 144B row stride, 16B aligned
#define SW 132    // fp32 epilogue scratch stride (128 + 4 pad words)

typedef __attribute__((ext_vector_type(8))) short short8;
typedef __attribute__((ext_vector_type(4))) float floatx4;
typedef __attribute__((ext_vector_type(4))) unsigned short ushort4v;

static __device__ __forceinline__ unsigned short f2bf(float f) {
    unsigned int u = __builtin_bit_cast(unsigned int, f);
    u = (u + 0x7fffu + ((u >> 16) & 1u)) >> 16;   // RNE
    return (unsigned short)u;
}

// Stage a 128x64 fp32 tile (row stride 64) -> bf16 LDS tile (row stride LDST)
static __device__ __forceinline__ void stage_tile(unsigned short* lds,
                                                  const float* __restrict__ g,
                                                  int tid) {
#pragma unroll
    for (int it = 0; it < 8; ++it) {
        int idx = it * 1024 + tid * 4;
        int row = idx >> 6, col = idx & 63;
        const float4 v = *reinterpret_cast<const float4*>(g + row * 64 + col);
        ushort4v o = { f2bf(v.x), f2bf(v.y), f2bf(v.z), f2bf(v.w) };
        *reinterpret_cast<ushort4v*>(lds + row * LDST + col) = o;
    }
}

// -- Kernel A: ctx = clip(sum_t sigmoid(qk/8)*t, 0, 2046) + per-tile min/max --
// Double-buffered K staging (1 barrier/iter), XCD-swizzled grid, exp2 sigmoid.
__global__ __launch_bounds__(256, 2)
void ctx_kernel(const float* __restrict__ q, const float* __restrict__ k,
                float* __restrict__ ctx, float2* __restrict__ mm) {
    __shared__ __align__(16) unsigned short Ab[128 * LDST];
    __shared__ __align__(16) unsigned short Kb[2][128 * LDST];
    __shared__ float sh_ctx[128];

    int bx = blockIdx.x;
    // swizzle: the 8 blocks sharing this bh's k-tiles are 64 apart -> same XCD
    int bh = bx & 63, mt = bx >> 6;
    int m0 = mt << 7;
    int tid = threadIdx.x;
    int lane = tid & 63, w = tid >> 6;
    int lo = lane & 15, quad = lane >> 4;

    const float* kb = k + (size_t)bh * Ss_ * DH;

    stage_tile(Ab, q + (size_t)(bh * Ss_ + m0) * DH, tid);
    stage_tile(Kb[0], kb, tid);
    __syncthreads();

    short8 afr[2][2];
#pragma unroll
    for (int i = 0; i < 2; ++i)
#pragma unroll
        for (int k2 = 0; k2 < 2; ++k2)
            afr[i][k2] = *reinterpret_cast<const short8*>(
                &Ab[(w * 32 + i * 16 + lo) * LDST + k2 * 32 + quad * 8]);

    float rp[2][4];
#pragma unroll
    for (int i = 0; i < 2; ++i)
#pragma unroll
        for (int r = 0; r < 4; ++r) rp[i][r] = 0.f;

    const float kSig = -0.18033688011112042f;  // -(1/8)*log2(e)

#pragma unroll 1
    for (int tt = 0; tt < 8; ++tt) {
        const unsigned short* cur = Kb[tt & 1];
        // Prefetch next k-tile into the other buffer (no barrier needed:
        // last round's end-of-iter barrier guarantees it is no longer read).
        if (tt < 7) stage_tile(Kb[(tt + 1) & 1], kb + (size_t)(tt + 1) * 128 * DH, tid);

        int t0 = tt << 7;
#pragma unroll
        for (int j = 0; j < 8; ++j) {
            short8 b0 = *reinterpret_cast<const short8*>(
                &cur[(j * 16 + lo) * LDST + 0 + quad * 8]);
            short8 b1 = *reinterpret_cast<const short8*>(
                &cur[(j * 16 + lo) * LDST + 32 + quad * 8]);
            float tcol = (float)(t0 + j * 16 + lo);
#pragma unroll
            for (int i = 0; i < 2; ++i) {
                floatx4 c = {0.f, 0.f, 0.f, 0.f};
                c = __builtin_amdgcn_mfma_f32_16x16x32_bf16(afr[i][0], b0, c, 0, 0, 0);
                c = __builtin_amdgcn_mfma_f32_16x16x32_bf16(afr[i][1], b1, c, 0, 0, 0);
#pragma unroll
                for (int r = 0; r < 4; ++r) {
                    float e = __builtin_amdgcn_exp2f(c[r] * kSig);
                    float g = __builtin_amdgcn_rcpf(1.0f + e);
                    rp[i][r] = fmaf(g, tcol, rp[i][r]);
                }
            }
        }
        __syncthreads();
    }

    // reduce across the 16 lanes (cols) sharing each row
#pragma unroll
    for (int i = 0; i < 2; ++i)
#pragma unroll
        for (int r = 0; r < 4; ++r) {
            float v = rp[i][r];
            v += __shfl_xor(v, 1);
            v += __shfl_xor(v, 2);
            v += __shfl_xor(v, 4);
            v += __shfl_xor(v, 8);
            rp[i][r] = v;
        }

    if (lo == 0) {
#pragma unroll
        for (int i = 0; i < 2; ++i)
#pragma unroll
            for (int r = 0; r < 4; ++r) {
                int lr = w * 32 + i * 16 + quad * 4 + r;
                float v = fminf(fmaxf(rp[i][r], 0.f), (float)(MAXLEN - 2));
                sh_ctx[lr] = v;
                ctx[bh * Ss_ + m0 + lr] = v;
            }
    }
    __syncthreads();

    // Block min/max of the 128 ctx values -> mm[bh*8+mt]
    if (tid < 64) {
        float a = sh_ctx[tid], b = sh_ctx[tid + 64];
        float mn = fminf(a, b), mx = fmaxf(a, b);
#pragma unroll
        for (int off = 1; off < 64; off <<= 1) {
            mn = fminf(mn, __shfl_xor(mn, off));
            mx = fmaxf(mx, __shfl_xor(mx, off));
        }
        if (tid == 0) mm[bh * 8 + mt] = make_float2(mn, mx);
    }
}

// -- Kernel B: bias = Q . pos_emb^T. Fast path when ctx is uniform over bh
//    (pos_emb rows all identical -> each output row is one constant):
//    fp32 dots + streaming row-constant NT writes. Else: proven R7 GEMM path.
__global__ __launch_bounds__(256, 4)
void bias_kernel(const float* __restrict__ q, const float* __restrict__ tb,
                 const float* __restrict__ ctx, const float2* __restrict__ mm,
                 float* __restrict__ out) {
    __shared__ __align__(16) unsigned char smem[2 * 128 * LDST * 2];

    int bx = blockIdx.x;
    int bh = bx >> 6;
    int mt = (bx >> 3) & 7;
    int nt = bx & 7;
    int m0 = mt << 7, n0 = nt << 7;
    int tid = threadIdx.x;
    int lane = tid & 63, w = tid >> 6;
    int lo = lane & 15, quad = lane >> 4;

    // Uniformity check over all 8 m-tiles of this bh (block-uniform result)
    float mn = 3.0e38f, mx = -3.0e38f;
#pragma unroll
    for (int j = 0; j < 8; ++j) {
        float2 p = mm[bh * 8 + j];
        mn = fminf(mn, p.x);
        mx = fmaxf(mx, p.y);
    }

    if (mn == mx) {
        // ---------- FAST PATH: pos_emb identical for every t ----------
        float* pr = reinterpret_cast<float*>(smem);        // [64] fp32 emb row
        float* sc = pr + 64;                               // [128] row constants

        float v = mn;
        int fl = (int)v;
        float fr = v - (float)fl;
        int ce = min(fl + 1, MAXLEN - 1);
        if (tid < 16) {
            int d0 = tid * 4;
            const float4 e0 = *reinterpret_cast<const float4*>(tb + fl * DH + d0);
            const float4 e1 = *reinterpret_cast<const float4*>(tb + ce * DH + d0);
            pr[d0 + 0] = e0.x + fr * (e1.x - e0.x);
            pr[d0 + 1] = e0.y + fr * (e1.y - e0.y);
            pr[d0 + 2] = e0.z + fr * (e1.z - e0.z);
            pr[d0 + 3] = e0.w + fr * (e1.w - e0.w);
        }
        __syncthreads();

        // fp32 dots: 2 threads per row (halves), combine via shfl_xor(1)
        {
            int row = tid >> 1, half = tid & 1;
            const float* qr = q + (size_t)(bh * Ss_ + m0 + row) * DH + half * 32;
            const float* ph = pr + half * 32;
            float s = 0.f;
#pragma unroll
            for (int d = 0; d < 32; d += 4) {
                const float4 qq = *reinterpret_cast<const float4*>(qr + d);
                s += qq.x * ph[d] + qq.y * ph[d + 1] + qq.z * ph[d + 2] +
                     qq.w * ph[d + 3];
            }
            s += __shfl_xor(s, 1);
            if (half == 0) sc[row] = s;
        }
        __syncthreads();

        // Stream the 128x128 tile: each wave-inst writes 1 KB of full lines
#pragma unroll
        for (int it = 0; it < 16; ++it) {
            int flat = (it * 256 + tid) * 4;
            int lrow = flat >> 7, col = flat & 127;
            float c = sc[lrow];
            floatx4 vv = {c, c, c, c};
            __builtin_nontemporal_store(
                vv, reinterpret_cast<floatx4*>(
                        out + (size_t)(bh * Ss_ + m0 + lrow) * Ss_ + n0 + col));
        }
        return;
    }

    // ---------- SLOW PATH: R7-proven tile GEMM ----------
    unsigned short* Ab = reinterpret_cast<unsigned short*>(smem);
    unsigned short* Pb = Ab + 128 * LDST;
    float* scratch = reinterpret_cast<float*>(smem);

    stage_tile(Ab, q + (size_t)(bh * Ss_ + m0) * DH, tid);

    {
        int rsub = tid >> 4;       // 0..15
        int d0 = (tid & 15) * 4;   // 0..60
#pragma unroll
        for (int pass = 0; pass < 8; ++pass) {
            int row = pass * 16 + rsub;
            float c = ctx[bh * Ss_ + n0 + row];
            int fl = (int)c;
            float fr = c - (float)fl;
            int ce = min(fl + 1, MAXLEN - 1);
            const float4 e0 = *reinterpret_cast<const float4*>(tb + fl * DH + d0);
            const float4 e1 = *reinterpret_cast<const float4*>(tb + ce * DH + d0);
            ushort4v o = { f2bf(e0.x + fr * (e1.x - e0.x)),
                           f2bf(e0.y + fr * (e1.y - e0.y)),
                           f2bf(e0.z + fr * (e1.z - e0.z)),
                           f2bf(e0.w + fr * (e1.w - e0.w)) };
            *reinterpret_cast<ushort4v*>(&Pb[row * LDST + d0]) = o;
        }
    }
    __syncthreads();

    short8 afr[2][2];
#pragma unroll
    for (int i = 0; i < 2; ++i)
#pragma unroll
        for (int k2 = 0; k2 < 2; ++k2)
            afr[i][k2] = *reinterpret_cast<const short8*>(
                &Ab[(w * 32 + i * 16 + lo) * LDST + k2 * 32 + quad * 8]);

    floatx4 acc[2][8];
#pragma unroll
    for (int i = 0; i < 2; ++i)
#pragma unroll
        for (int j = 0; j < 8; ++j) acc[i][j] = (floatx4){0.f, 0.f, 0.f, 0.f};

#pragma unroll
    for (int j = 0; j < 8; ++j) {
        short8 b0 = *reinterpret_cast<const short8*>(
            &Pb[(j * 16 + lo) * LDST + 0 + quad * 8]);
        short8 b1 = *reinterpret_cast<const short8*>(
            &Pb[(j * 16 + lo) * LDST + 32 + quad * 8]);
#pragma unroll
        for (int i = 0; i < 2; ++i) {
            acc[i][j] = __builtin_amdgcn_mfma_f32_16x16x32_bf16(afr[i][0], b0, acc[i][j], 0, 0, 0);
            acc[i][j] = __builtin_amdgcn_mfma_f32_16x16x32_bf16(afr[i][1], b1, acc[i][j], 0, 0, 0);
        }
    }

    // Epilogue: LDS transpose -> contiguous dwordx4 nontemporal stores.
#pragma unroll
    for (int i = 0; i < 2; ++i) {
        __syncthreads();
#pragma unroll
        for (int j = 0; j < 8; ++j)
#pragma unroll
            for (int r = 0; r < 4; ++r) {
                int lrow = w * 16 + quad * 4 + r;
                scratch[lrow * SW + j * 16 + lo] = acc[i][j][r];
            }
        __syncthreads();
#pragma unroll
        for (int it = 0; it < 8; ++it) {
            int flat = it * 1024 + tid * 4;
            int lrow = flat >> 7, col = flat & 127;
            floatx4 vv = *reinterpret_cast<const floatx4*>(&scratch[lrow * SW + col]);
            int grow = m0 + (lrow >> 4) * 32 + i * 16 + (lrow & 15);
            __builtin_nontemporal_store(
                vv, reinterpret_cast<floatx4*>(
                        out + (size_t)(bh * Ss_ + grow) * Ss_ + n0 + col));
        }
    }
}

extern "C" void kernel_launch(void* const* d_in, const int* in_sizes, int n_in,
                              void* d_out, int out_size, void* d_ws, size_t ws_size,
                              hipStream_t stream) {
    const float* q  = (const float*)d_in[0];
    const float* k  = (const float*)d_in[1];
    const float* tb = (const float*)d_in[2];
    float* ctx = (float*)d_ws;                       // BH*S floats = 256 KB
    float2* mm = (float2*)((float*)d_ws + BH * Ss_); // BH*8 float2
    float* out = (float*)d_out;

    ctx_kernel<<<BH * 8, 256, 0, stream>>>(q, k, ctx, mm);
    bias_kernel<<<BH * 64, 256, 0, stream>>>(q, tb, ctx, mm, out);
}

// Round 11
// 310.484 us; speedup vs baseline: 1.2513x; 1.0375x over previous
//
#include <hip/hip_runtime.h>

#define Bb_ 4
#define Hh_ 16
#define Ss_ 1024
#define DH 64
#define MAXLEN 2048
#define BH (Bb_*Hh_)
#define LDST 72   // 64 + 8 pad (bf16 elems) -> 144B row stride, 16B aligned
#define SW 132    // fp32 epilogue scratch stride (128 + 4 pad words)

typedef __attribute__((ext_vector_type(8))) short short8;
typedef __attribute__((ext_vector_type(4))) float floatx4;
typedef __attribute__((ext_vector_type(4))) unsigned short ushort4v;

static __device__ __forceinline__ unsigned short f2bf(float f) {
    unsigned int u = __builtin_bit_cast(unsigned int, f);
    u = (u + 0x7fffu + ((u >> 16) & 1u)) >> 16;   // RNE
    return (unsigned short)u;
}

// Stage a 128x64 fp32 tile (row stride 64) -> bf16 LDS tile (row stride LDST)
static __device__ __forceinline__ void stage_tile(unsigned short* lds,
                                                  const float* __restrict__ g,
                                                  int tid) {
#pragma unroll
    for (int it = 0; it < 8; ++it) {
        int idx = it * 1024 + tid * 4;
        int row = idx >> 6, col = idx & 63;
        const float4 v = *reinterpret_cast<const float4*>(g + row * 64 + col);
        ushort4v o = { f2bf(v.x), f2bf(v.y), f2bf(v.z), f2bf(v.w) };
        *reinterpret_cast<ushort4v*>(lds + row * LDST + col) = o;
    }
}

// Fused CoPE: block (bh, nt) computes ctx[bh, n-slice] locally (phase 1),
// builds pos_emb for its columns (phase 2), then emits the full 1024 x 128
// output column-strip (phase 3). No inter-kernel dependency, no workspace.
// LDS union (73728 B, 2 blocks/CU):
//   [0,      18432) Ab   : q-tile bf16 (phases 1 & 3)
//   [18432,  55296) Kb[2]: k double-buffer (phase 1) / scratch fp32 (phase 3)
//   [55296,  73728) Pb   : pos_emb bf16 tile (phase 3 slow path)
__global__ __launch_bounds__(256, 2)
void cope_kernel(const float* __restrict__ q, const float* __restrict__ k,
                 const float* __restrict__ tb, float* __restrict__ out) {
    __shared__ __align__(16) unsigned char smem[73728];
    __shared__ float sh_ctx[128];
    __shared__ float sh_sc[128];
    __shared__ float2 sh_mm;

    unsigned short* Ab = reinterpret_cast<unsigned short*>(smem);
    unsigned short* Kb0 = reinterpret_cast<unsigned short*>(smem + 18432);
    unsigned short* Kb1 = reinterpret_cast<unsigned short*>(smem + 36864);
    float* scratch = reinterpret_cast<float*>(smem + 18432);
    unsigned short* Pb = reinterpret_cast<unsigned short*>(smem + 55296);
    float* pr = sh_sc;  // fast path: fp32 emb row cache (64 floats)

    int bx = blockIdx.x;
    // swizzle: blocks sharing this bh's k-stream are 64 apart -> same XCD
    int bh = bx & 63, nt = bx >> 6;
    int n0 = nt << 7;
    int tid = threadIdx.x;
    int lane = tid & 63, w = tid >> 6;
    int lo = lane & 15, quad = lane >> 4;

    const float* kb = k + (size_t)bh * Ss_ * DH;
    const float* qb = q + (size_t)bh * Ss_ * DH;

    // ---------------- Phase 1: ctx for rows n0..n0+127 ----------------
    stage_tile(Ab, qb + (size_t)n0 * DH, tid);
    stage_tile(Kb0, kb, tid);
    __syncthreads();

    short8 afr[2][2];
#pragma unroll
    for (int i = 0; i < 2; ++i)
#pragma unroll
        for (int k2 = 0; k2 < 2; ++k2)
            afr[i][k2] = *reinterpret_cast<const short8*>(
                &Ab[(w * 32 + i * 16 + lo) * LDST + k2 * 32 + quad * 8]);

    float rp[2][4];
#pragma unroll
    for (int i = 0; i < 2; ++i)
#pragma unroll
        for (int r = 0; r < 4; ++r) rp[i][r] = 0.f;

    const float kSig = -0.18033688011112042f;  // -(1/8)*log2(e)

#pragma unroll 1
    for (int tt = 0; tt < 8; ++tt) {
        const unsigned short* cur = (tt & 1) ? Kb1 : Kb0;
        if (tt < 7)
            stage_tile((tt & 1) ? Kb0 : Kb1, kb + (size_t)(tt + 1) * 128 * DH, tid);

        int t0 = tt << 7;
#pragma unroll
        for (int j = 0; j < 8; ++j) {
            short8 b0 = *reinterpret_cast<const short8*>(
                &cur[(j * 16 + lo) * LDST + 0 + quad * 8]);
            short8 b1 = *reinterpret_cast<const short8*>(
                &cur[(j * 16 + lo) * LDST + 32 + quad * 8]);
            float tcol = (float)(t0 + j * 16 + lo);
#pragma unroll
            for (int i = 0; i < 2; ++i) {
                floatx4 c = {0.f, 0.f, 0.f, 0.f};
                c = __builtin_amdgcn_mfma_f32_16x16x32_bf16(afr[i][0], b0, c, 0, 0, 0);
                c = __builtin_amdgcn_mfma_f32_16x16x32_bf16(afr[i][1], b1, c, 0, 0, 0);
#pragma unroll
                for (int r = 0; r < 4; ++r) {
                    float e = __builtin_amdgcn_exp2f(c[r] * kSig);
                    float g = __builtin_amdgcn_rcpf(1.0f + e);
                    rp[i][r] = fmaf(g, tcol, rp[i][r]);
                }
            }
        }
        __syncthreads();
    }

#pragma unroll
    for (int i = 0; i < 2; ++i)
#pragma unroll
        for (int r = 0; r < 4; ++r) {
            float v = rp[i][r];
            v += __shfl_xor(v, 1);
            v += __shfl_xor(v, 2);
            v += __shfl_xor(v, 4);
            v += __shfl_xor(v, 8);
            rp[i][r] = v;
        }

    if (lo == 0) {
#pragma unroll
        for (int i = 0; i < 2; ++i)
#pragma unroll
            for (int r = 0; r < 4; ++r) {
                int lr = w * 32 + i * 16 + quad * 4 + r;
                sh_ctx[lr] = fminf(fmaxf(rp[i][r], 0.f), (float)(MAXLEN - 2));
            }
    }
    __syncthreads();

    // Local min/max over the 128 ctx values
    if (tid < 64) {
        float a = sh_ctx[tid], b = sh_ctx[tid + 64];
        float mn = fminf(a, b), mx = fmaxf(a, b);
#pragma unroll
        for (int off = 1; off < 64; off <<= 1) {
            mn = fminf(mn, __shfl_xor(mn, off));
            mx = fmaxf(mx, __shfl_xor(mx, off));
        }
        if (tid == 0) sh_mm = make_float2(mn, mx);
    }
    __syncthreads();

    float2 mmv = sh_mm;

    if (mmv.x == mmv.y) {
        // ------- FAST PATH: all local ctx equal -> row-constant strip -------
        float v = mmv.x;
        int fl = (int)v;
        float fr = v - (float)fl;
        int ce = min(fl + 1, MAXLEN - 1);
        if (tid < 16) {
            int d0 = tid * 4;
            const float4 e0 = *reinterpret_cast<const float4*>(tb + fl * DH + d0);
            const float4 e1 = *reinterpret_cast<const float4*>(tb + ce * DH + d0);
            pr[d0 + 0] = e0.x + fr * (e1.x - e0.x);
            pr[d0 + 1] = e0.y + fr * (e1.y - e0.y);
            pr[d0 + 2] = e0.z + fr * (e1.z - e0.z);
            pr[d0 + 3] = e0.w + fr * (e1.w - e0.w);
        }
        __syncthreads();

        // cache emb row in registers (8 floats per pair of threads' use)
        float ph[32];
        {
            int half = tid & 1;
#pragma unroll
            for (int d = 0; d < 32; ++d) ph[d] = pr[half * 32 + d];
        }

#pragma unroll 1
        for (int mt = 0; mt < 8; ++mt) {
            int m0 = mt << 7;
            // fp32 dots: 2 threads per row (halves), 256 threads = 128 rows
            {
                int row = tid >> 1, half = tid & 1;
                const float* qr = qb + (size_t)(m0 + row) * DH + half * 32;
                float s = 0.f;
#pragma unroll
                for (int d = 0; d < 32; d += 4) {
                    const float4 qq = *reinterpret_cast<const float4*>(qr + d);
                    s += qq.x * ph[d] + qq.y * ph[d + 1] + qq.z * ph[d + 2] +
                         qq.w * ph[d + 3];
                }
                s += __shfl_xor(s, 1);
                if (half == 0) sh_sc[64 + (row >> 1)] = 0.f;  // dummy to keep pr intact? no-op
                if (half == 0) sh_ctx[row] = s;               // reuse sh_ctx as sc
            }
            __syncthreads();

            // Stream 128x128: each wave-inst writes 1 KB of full lines
#pragma unroll
            for (int it = 0; it < 16; ++it) {
                int flat = (it * 256 + tid) * 4;
                int lrow = flat >> 7, col = flat & 127;
                float c = sh_ctx[lrow];
                floatx4 vv = {c, c, c, c};
                __builtin_nontemporal_store(
                    vv, reinterpret_cast<floatx4*>(
                            out + (size_t)(bh * Ss_ + m0 + lrow) * Ss_ + n0 + col));
            }
            __syncthreads();
        }
        return;
    }

    // ------- SLOW PATH: build Pb, then 8 m-tiles of MFMA GEMM -------
    {
        int rsub = tid >> 4;       // 0..15
        int d0 = (tid & 15) * 4;   // 0..60
#pragma unroll
        for (int pass = 0; pass < 8; ++pass) {
            int row = pass * 16 + rsub;
            float c = sh_ctx[row];
            int fl = (int)c;
            float fr = c - (float)fl;
            int ce = min(fl + 1, MAXLEN - 1);
            const float4 e0 = *reinterpret_cast<const float4*>(tb + fl * DH + d0);
            const float4 e1 = *reinterpret_cast<const float4*>(tb + ce * DH + d0);
            ushort4v o = { f2bf(e0.x + fr * (e1.x - e0.x)),
                           f2bf(e0.y + fr * (e1.y - e0.y)),
                           f2bf(e0.z + fr * (e1.z - e0.z)),
                           f2bf(e0.w + fr * (e1.w - e0.w)) };
            *reinterpret_cast<ushort4v*>(&Pb[row * LDST + d0]) = o;
        }
    }
    __syncthreads();

    // B-fragments are loop-invariant across m-tiles: hoist to registers
    short8 bfr[8][2];
#pragma unroll
    for (int j = 0; j < 8; ++j) {
        bfr[j][0] = *reinterpret_cast<const short8*>(
            &Pb[(j * 16 + lo) * LDST + 0 + quad * 8]);
        bfr[j][1] = *reinterpret_cast<const short8*>(
            &Pb[(j * 16 + lo) * LDST + 32 + quad * 8]);
    }

#pragma unroll 1
    for (int mt = 0; mt < 8; ++mt) {
        int m0 = mt << 7;
        stage_tile(Ab, qb + (size_t)m0 * DH, tid);
        __syncthreads();

        short8 mfr[2][2];
#pragma unroll
        for (int i = 0; i < 2; ++i)
#pragma unroll
            for (int k2 = 0; k2 < 2; ++k2)
                mfr[i][k2] = *reinterpret_cast<const short8*>(
                    &Ab[(w * 32 + i * 16 + lo) * LDST + k2 * 32 + quad * 8]);

        floatx4 acc[2][8];
#pragma unroll
        for (int i = 0; i < 2; ++i)
#pragma unroll
            for (int j = 0; j < 8; ++j) acc[i][j] = (floatx4){0.f, 0.f, 0.f, 0.f};

#pragma unroll
        for (int j = 0; j < 8; ++j)
#pragma unroll
            for (int i = 0; i < 2; ++i) {
                acc[i][j] = __builtin_amdgcn_mfma_f32_16x16x32_bf16(
                    mfr[i][0], bfr[j][0], acc[i][j], 0, 0, 0);
                acc[i][j] = __builtin_amdgcn_mfma_f32_16x16x32_bf16(
                    mfr[i][1], bfr[j][1], acc[i][j], 0, 0, 0);
            }

        // Epilogue: LDS transpose -> contiguous dwordx4 NT stores
#pragma unroll
        for (int i = 0; i < 2; ++i) {
            __syncthreads();
#pragma unroll
            for (int j = 0; j < 8; ++j)
#pragma unroll
                for (int r = 0; r < 4; ++r) {
                    int lrow = w * 16 + quad * 4 + r;
                    scratch[lrow * SW + j * 16 + lo] = acc[i][j][r];
                }
            __syncthreads();
#pragma unroll
            for (int it = 0; it < 8; ++it) {
                int flat = it * 1024 + tid * 4;
                int lrow = flat >> 7, col = flat & 127;
                floatx4 vv =
                    *reinterpret_cast<const floatx4*>(&scratch[lrow * SW + col]);
                int grow = m0 + (lrow >> 4) * 32 + i * 16 + (lrow & 15);
                __builtin_nontemporal_store(
                    vv, reinterpret_cast<floatx4*>(
                            out + (size_t)(bh * Ss_ + grow) * Ss_ + n0 + col));
            }
        }
        __syncthreads();  // scratch/Ab safe for next mt
    }
}

extern "C" void kernel_launch(void* const* d_in, const int* in_sizes, int n_in,
                              void* d_out, int out_size, void* d_ws, size_t ws_size,
                              hipStream_t stream) {
    const float* q  = (const float*)d_in[0];
    const float* k  = (const float*)d_in[1];
    const float* tb = (const float*)d_in[2];
    float* out = (float*)d_out;

    cope_kernel<<<BH * 8, 256, 0, stream>>>(q, k, tb, out);
}